// Round 8
// baseline (636.334 us; speedup 1.0000x reference)
//
#include <hip/hip_runtime.h>
#include <hip/hip_bf16.h>

// GQA attention layer, B=2 S=2048 D=2048, H=32 KVH=8 DH=64, causal, RoPE.
// Inputs fp32; OUTPUT fp32 (reference returns float32 — round-8 fix).
// Internals: bf16 MFMA pipeline with fp32 accumulation.

typedef __attribute__((ext_vector_type(8))) short short8;
typedef __attribute__((ext_vector_type(4))) short short4v;
typedef __attribute__((ext_vector_type(4))) float floatx4;

#define GLDS16(g, s) __builtin_amdgcn_global_load_lds( \
    (const __attribute__((address_space(1))) void*)(g), \
    (__attribute__((address_space(3))) void*)(s), 16, 0, 0)

__device__ __forceinline__ float bf2f(short v) {
  union { unsigned int u; float f; } x;
  x.u = ((unsigned int)(unsigned short)v) << 16;
  return x.f;
}
__device__ __forceinline__ short f2bf(float f) {
  union { float f; unsigned int u; } x; x.f = f;
  unsigned int r = x.u + 0x7fffu + ((x.u >> 16) & 1u);  // RNE
  return (short)(r >> 16);
}

// ---------------- GEMM core: Y[m][n] = sum_k X[m][k] * W[n][k] ----------------
// 128x128 tile, BK=32, 256 threads (4 waves, 2x2), 16x16x32 bf16 MFMA.
// XBF: X bf16 via GLDS16, else fp32 reg-staged+converted. W always fp32.
// OUTF32: write fp32 (final output) vs bf16 (workspace).
template <bool XBF, bool OUTF32>
__device__ __forceinline__ void gemm_core_128(
    const void* __restrict__ Xv, const float* __restrict__ W,
    void* __restrict__ Yv, int m0, int n0, int K,
    int ldx, int ldw, int ldy, short* As, short* Bs)
{
  const int tid = threadIdx.x;
  const int w = tid >> 6, l = tid & 63;
  const int lrow = l & 15, lgrp = l >> 4;
  const int wr = w >> 1, wc = w & 1;

  floatx4 acc[4][4];
#pragma unroll
  for (int i = 0; i < 4; ++i)
#pragma unroll
    for (int j = 0; j < 4; ++j) acc[i][j] = (floatx4){0.f, 0.f, 0.f, 0.f};

  for (int k0 = 0; k0 < K; k0 += 32) {
    if (XBF) {
      const short* Xb = (const short*)Xv;
#pragma unroll
      for (int i = 0; i < 2; ++i) {
        int chunk = i * 256 + w * 64 + l;     // [0,512)
        GLDS16(Xb + (size_t)(m0 + (chunk >> 2)) * ldx + k0 + (chunk & 3) * 8,
               (char*)As + (i * 256 + w * 64) * 16);
      }
    } else {
      const float* Xf = (const float*)Xv;
#pragma unroll
      for (int i = 0; i < 4; ++i) {
        int chunk = i * 256 + tid;            // [0,1024)
        int row = chunk >> 3, f4 = chunk & 7; // 8x float4 per 32-float row
        floatx4 xv = *(const floatx4*)(Xf + (size_t)(m0 + row) * ldx + k0 + f4 * 4);
        short4v xo;
#pragma unroll
        for (int j = 0; j < 4; ++j) xo[j] = f2bf(xv[j]);
        *(short4v*)(As + chunk * 4) = xo;
      }
    }
#pragma unroll
    for (int i = 0; i < 4; ++i) {
      int chunk = i * 256 + tid;
      int row = chunk >> 3, f4 = chunk & 7;
      floatx4 wv = *(const floatx4*)(W + (size_t)(n0 + row) * ldw + k0 + f4 * 4);
      short4v wb;
#pragma unroll
      for (int j = 0; j < 4; ++j) wb[j] = f2bf(wv[j]);
      *(short4v*)(Bs + chunk * 4) = wb;
    }
    __syncthreads();  // drains vmcnt (GLDS) + lgkmcnt (ds_write) -> LDS valid

    short8 af[4], bfr[4];
#pragma unroll
    for (int mi = 0; mi < 4; ++mi)
      af[mi] = *(const short8*)(As + (wr * 64 + mi * 16 + lrow) * 32 + lgrp * 8);
#pragma unroll
    for (int ni = 0; ni < 4; ++ni)
      bfr[ni] = *(const short8*)(Bs + (wc * 64 + ni * 16 + lrow) * 32 + lgrp * 8);
#pragma unroll
    for (int mi = 0; mi < 4; ++mi)
#pragma unroll
      for (int ni = 0; ni < 4; ++ni)
        acc[mi][ni] = __builtin_amdgcn_mfma_f32_16x16x32_bf16(
            af[mi], bfr[ni], acc[mi][ni], 0, 0, 0);
    __syncthreads();
  }

  // epilogue: C/D layout col=lane&15, row=(lane>>4)*4+reg
#pragma unroll
  for (int mi = 0; mi < 4; ++mi) {
#pragma unroll
    for (int ni = 0; ni < 4; ++ni) {
      int row = m0 + wr * 64 + mi * 16 + lgrp * 4;
      int col = n0 + wc * 64 + ni * 16 + lrow;
#pragma unroll
      for (int r = 0; r < 4; ++r) {
        if (OUTF32)
          ((float*)Yv)[(size_t)(row + r) * ldy + col] = acc[mi][ni][r];
        else
          ((short*)Yv)[(size_t)(row + r) * ldy + col] = f2bf(acc[mi][ni][r]);
      }
    }
  }
}

// ---------------- fused QKV projection ----------------
__global__ __launch_bounds__(256) void qkv_kernel(
    const float* __restrict__ x, const float* __restrict__ wq,
    const float* __restrict__ wk, const float* __restrict__ wv,
    short* __restrict__ q, short* __restrict__ k, short* __restrict__ v)
{
  __shared__ __align__(16) short As[128 * 32];
  __shared__ __align__(16) short Bs[128 * 32];
  int nt = blockIdx.x, mt = blockIdx.y;
  const float* W; short* Y; int n0, ldy;
  if (nt < 16)      { W = wq; Y = q; n0 = nt * 128;        ldy = 2048; }
  else if (nt < 20) { W = wk; Y = k; n0 = (nt - 16) * 128; ldy = 512;  }
  else              { W = wv; Y = v; n0 = (nt - 20) * 128; ldy = 512;  }
  gemm_core_128<false, false>(x, W, Y, mt * 128, n0, 2048, 2048, 2048, ldy, As, Bs);
}

// ---------------- output projection (A = bf16 attn-out, W = fp32, Y = fp32) ---
__global__ __launch_bounds__(256) void oproj_kernel(
    const short* __restrict__ a, const float* __restrict__ wo, float* __restrict__ y)
{
  __shared__ __align__(16) short As[128 * 32];
  __shared__ __align__(16) short Bs[128 * 32];
  gemm_core_128<true, true>(a, wo, y, blockIdx.y * 128, blockIdx.x * 128,
                            2048, 2048, 2048, 2048, As, Bs);
}

// ---------------- RoPE (in-place on q and k; fp32 cos/sin tables) -------------
__global__ void rope_kernel(short* __restrict__ q, short* __restrict__ k,
                            const float* __restrict__ ct, const float* __restrict__ st)
{
  const int NQ = 4096 * 1024;
  const int NK = 4096 * 256;
  int idx = blockIdx.x * blockDim.x + threadIdx.x;
  int total = NQ + NK;
  for (int p = idx; p < total; p += gridDim.x * blockDim.x) {
    short* base; int tok, i, off;
    if (p < NQ) {
      tok = p >> 10; int rem = p & 1023;
      i = rem & 31;
      base = q; off = tok * 2048 + rem * 2;
    } else {
      int pp = p - NQ;
      tok = pp >> 8; int rem = pp & 255;
      i = rem & 31;
      base = k; off = tok * 512 + rem * 2;
    }
    int s = tok & 2047;
    float c  = ct[s * 32 + i];
    float sn = st[s * 32 + i];
    unsigned int u = *(unsigned int*)(base + off);
    float xr = bf2f((short)(u & 0xffff));
    float xi = bf2f((short)(u >> 16));
    float orr = xr * c - xi * sn;
    float oi  = xr * sn + xi * c;
    unsigned int o = ((unsigned int)(unsigned short)f2bf(orr)) |
                     (((unsigned int)(unsigned short)f2bf(oi)) << 16);
    *(unsigned int*)(base + off) = o;
  }
}

// ---------------- flash attention (causal, GQA 4:1) ----------------
__global__ __launch_bounds__(256) void attn_kernel(
    const short* qws, const short* __restrict__ kws,
    const short* __restrict__ vws, short* ows)
{
  const int S = 2048;
  int bx = blockIdx.x;
  int qt = bx & 31;
  int hq = (bx >> 5) & 31;
  int b  = bx >> 10;
  int h  = hq >> 2;
  int tid = threadIdx.x;
  int w = tid >> 6, l = tid & 63;
  int lrow = l & 15, lgrp = l >> 4;

  __shared__ __align__(16) short Ks[64 * 64];
  __shared__ __align__(16) short Vt[64 * 72];
  __shared__ __align__(16) short Ps[4 * 16 * 72];

  short* myPs = Ps + w * 16 * 72;
  int qrow0 = qt * 64 + w * 16;

  short8 qf[2];
  {
    const short* qp = qws + ((size_t)(b * S + qrow0 + lrow) * 32 + hq) * 64 + lgrp * 8;
    qf[0] = *(const short8*)(qp);
    qf[1] = *(const short8*)(qp + 32);
  }

  floatx4 oacc[4];
#pragma unroll
  for (int d0 = 0; d0 < 4; ++d0) oacc[d0] = (floatx4){0.f, 0.f, 0.f, 0.f};
  float m_run[4], l_run[4];
#pragma unroll
  for (int r = 0; r < 4; ++r) { m_run[r] = -1e30f; l_run[r] = 0.f; }

  int kvEnd = qt * 64 + 64;
  for (int kv0 = 0; kv0 < kvEnd; kv0 += 64) {
#pragma unroll
    for (int i = 0; i < 2; ++i) {
      int chunk = i * 256 + w * 64 + l;
      int jr = chunk >> 3, dc = chunk & 7;
      GLDS16(kws + ((size_t)(b * S + kv0 + jr) * 8 + h) * 64 + dc * 8,
             (char*)Ks + (i * 256 + w * 64) * 16);
    }
#pragma unroll
    for (int i = 0; i < 2; ++i) {
      int chunk = i * 256 + tid;
      int jr = chunk >> 3, dc = chunk & 7;
      short8 vv = *(const short8*)(vws + ((size_t)(b * S + kv0 + jr) * 8 + h) * 64 + dc * 8);
#pragma unroll
      for (int e = 0; e < 8; ++e)
        Vt[(dc * 8 + e) * 72 + jr] = vv[e];
    }
    __syncthreads();

    floatx4 sf[4];
#pragma unroll
    for (int nj = 0; nj < 4; ++nj) {
      floatx4 sa = (floatx4){0.f, 0.f, 0.f, 0.f};
#pragma unroll
      for (int kk = 0; kk < 2; ++kk) {
        short8 kf = *(const short8*)(Ks + (nj * 16 + lrow) * 64 + kk * 32 + lgrp * 8);
        sa = __builtin_amdgcn_mfma_f32_16x16x32_bf16(qf[kk], kf, sa, 0, 0, 0);
      }
      sf[nj] = sa;
    }
    int qi0 = qrow0 + lgrp * 4;
#pragma unroll
    for (int nj = 0; nj < 4; ++nj) {
      int kj = kv0 + nj * 16 + lrow;
#pragma unroll
      for (int r = 0; r < 4; ++r) {
        float sv = sf[nj][r] * 0.125f;
        sf[nj][r] = (kj <= qi0 + r) ? sv : -1e30f;
      }
    }
    float tmax[4];
#pragma unroll
    for (int r = 0; r < 4; ++r)
      tmax[r] = fmaxf(fmaxf(sf[0][r], sf[1][r]), fmaxf(sf[2][r], sf[3][r]));
#pragma unroll
    for (int msk = 1; msk <= 8; msk <<= 1)
#pragma unroll
      for (int r = 0; r < 4; ++r)
        tmax[r] = fmaxf(tmax[r], __shfl_xor(tmax[r], msk, 64));
    float corr[4];
#pragma unroll
    for (int r = 0; r < 4; ++r) {
      float mnew = fmaxf(m_run[r], tmax[r]);
      corr[r] = __expf(m_run[r] - mnew);
      m_run[r] = mnew;
    }
    float rsum[4] = {0.f, 0.f, 0.f, 0.f};
#pragma unroll
    for (int nj = 0; nj < 4; ++nj)
#pragma unroll
      for (int r = 0; r < 4; ++r) {
        float pv = __expf(sf[nj][r] - m_run[r]);
        sf[nj][r] = pv;
        rsum[r] += pv;
      }
#pragma unroll
    for (int msk = 1; msk <= 8; msk <<= 1)
#pragma unroll
      for (int r = 0; r < 4; ++r)
        rsum[r] += __shfl_xor(rsum[r], msk, 64);
#pragma unroll
    for (int r = 0; r < 4; ++r) l_run[r] = l_run[r] * corr[r] + rsum[r];
#pragma unroll
    for (int d0 = 0; d0 < 4; ++d0)
#pragma unroll
      for (int r = 0; r < 4; ++r) oacc[d0][r] *= corr[r];

    // P (C-layout) -> LDS
#pragma unroll
    for (int nj = 0; nj < 4; ++nj)
#pragma unroll
      for (int r = 0; r < 4; ++r)
        myPs[(lgrp * 4 + r) * 72 + nj * 16 + lrow] = f2bf(sf[nj][r]);
    __syncthreads();  // fence: cross-lane P store -> load

#pragma unroll
    for (int kk2 = 0; kk2 < 2; ++kk2) {
      short8 pa = *(const short8*)(myPs + lrow * 72 + kk2 * 32 + lgrp * 8);
#pragma unroll
      for (int d0 = 0; d0 < 4; ++d0) {
        short8 vf = *(const short8*)(Vt + (d0 * 16 + lrow) * 72 + kk2 * 32 + lgrp * 8);
        oacc[d0] = __builtin_amdgcn_mfma_f32_16x16x32_bf16(pa, vf, oacc[d0], 0, 0, 0);
      }
    }
    __syncthreads();
  }

#pragma unroll
  for (int d0 = 0; d0 < 4; ++d0)
#pragma unroll
    for (int r = 0; r < 4; ++r) {
      float ov = oacc[d0][r] / l_run[r];
      ows[((size_t)(b * S + qrow0 + lgrp * 4 + r) * 32 + hq) * 64 + d0 * 16 + lrow] =
          f2bf(ov);
    }
}

extern "C" void kernel_launch(void* const* d_in, const int* in_sizes, int n_in,
                              void* d_out, int out_size, void* d_ws, size_t ws_size,
                              hipStream_t stream) {
  (void)in_sizes; (void)n_in; (void)out_size; (void)ws_size;
  const float* x  = (const float*)d_in[0];
  const float* wq = (const float*)d_in[1];
  const float* wk = (const float*)d_in[2];
  const float* wv = (const float*)d_in[3];
  const float* wo = (const float*)d_in[4];
  const float* ct = (const float*)d_in[5];
  const float* st = (const float*)d_in[6];
  float* out = (float*)d_out;  // fp32 output (reference returns float32)

  // workspace (bf16 shorts): q (attn-out in-place) + k + v = 25.2 MB total
  short* q_ws = (short*)d_ws;                      // 4096 x 2048
  short* k_ws = q_ws + (size_t)4096 * 2048;        // 4096 x 512
  short* v_ws = k_ws + (size_t)4096 * 512;         // 4096 x 512

  qkv_kernel<<<dim3(24, 32), 256, 0, stream>>>(x, wq, wk, wv, q_ws, k_ws, v_ws);
  rope_kernel<<<dim3(2048), 256, 0, stream>>>(q_ws, k_ws, ct, st);
  attn_kernel<<<dim3(2048), 256, 0, stream>>>(q_ws, k_ws, v_ws, q_ws);
  oproj_kernel<<<dim3(16, 32), 256, 0, stream>>>(q_ws, wo, out);
}

// Round 10
// 496.458 us; speedup vs baseline: 1.2817x; 1.2817x over previous
//
#include <hip/hip_runtime.h>
#include <hip/hip_bf16.h>

// GQA attention layer, B=2 S=2048 D=2048, H=32 KVH=8 DH=64, causal, RoPE.
// Inputs fp32; output fp32. Internals bf16 MFMA.
// R9: V stored transposed globally; K/V^T LDS tiles XOR-swizzled via
// pre-swizzled global_load_lds source; causal-paired attn blocks; GEMM LDS
// swizzle for 64-B-row tiles.

typedef __attribute__((ext_vector_type(8))) short short8;
typedef __attribute__((ext_vector_type(4))) short short4v;
typedef __attribute__((ext_vector_type(4))) float floatx4;

#define GLDS16(g, s) __builtin_amdgcn_global_load_lds( \
    (const __attribute__((address_space(1))) void*)(g), \
    (__attribute__((address_space(3))) void*)(s), 16, 0, 0)

__device__ __forceinline__ float bf2f(short v) {
  union { unsigned int u; float f; } x;
  x.u = ((unsigned int)(unsigned short)v) << 16;
  return x.f;
}
__device__ __forceinline__ short f2bf(float f) {
  union { float f; unsigned int u; } x; x.f = f;
  unsigned int r = x.u + 0x7fffu + ((x.u >> 16) & 1u);  // RNE
  return (short)(r >> 16);
}

// ---------------- GEMM core: Y[m][n] = sum_k X[m][k] * W[n][k] ----------------
// 128x128 tile, BK=32, 256 threads (4 waves, 2x2), 16x16x32 bf16 MFMA.
// LDS tiles swizzled: 16B-unit c16 ^= (row>>1)&3  (64-B rows -> 2-way max).
// XBF: X bf16 via GLDS16 (source pre-swizzled); else fp32 reg-staged.
// EPI: 0 = bf16 row-major, 1 = fp32 row-major, 2 = bf16 transposed packed
//      (Y[col*ldy + row], 4 consecutive rows per store).
template <bool XBF, int EPI>
__device__ __forceinline__ void gemm_core_128(
    const void* __restrict__ Xv, const float* __restrict__ W,
    void* __restrict__ Yv, int m0, int n0, int K,
    int ldx, int ldw, int ldy, short* As, short* Bs)
{
  const int tid = threadIdx.x;
  const int w = tid >> 6, l = tid & 63;
  const int lrow = l & 15, lgrp = l >> 4;
  const int wr = w >> 1, wc = w & 1;

  floatx4 acc[4][4];
#pragma unroll
  for (int i = 0; i < 4; ++i)
#pragma unroll
    for (int j = 0; j < 4; ++j) acc[i][j] = (floatx4){0.f, 0.f, 0.f, 0.f};

  for (int k0 = 0; k0 < K; k0 += 32) {
    if (XBF) {
      const short* Xb = (const short*)Xv;
#pragma unroll
      for (int i = 0; i < 2; ++i) {
        int cc = i * 256 + w * 64 + l;              // [0,512)
        int row = cc >> 2;
        int sc16 = (cc & 3) ^ ((row >> 1) & 3);     // inverse swizzle on source
        GLDS16(Xb + (size_t)(m0 + row) * ldx + k0 + sc16 * 8,
               (char*)As + (i * 256 + w * 64) * 16);
      }
    } else {
      const float* Xf = (const float*)Xv;
#pragma unroll
      for (int i = 0; i < 4; ++i) {
        int chunk = i * 256 + tid;                  // [0,1024)
        int row = chunk >> 3, f4 = chunk & 7;       // 8x 4-elem units per row
        floatx4 xv = *(const floatx4*)(Xf + (size_t)(m0 + row) * ldx + k0 + f4 * 4);
        short4v xo;
#pragma unroll
        for (int j = 0; j < 4; ++j) xo[j] = f2bf(xv[j]);
        int soff = row * 32 + (((f4 >> 1) ^ ((row >> 1) & 3)) << 3) + (f4 & 1) * 4;
        *(short4v*)(As + soff) = xo;
      }
    }
#pragma unroll
    for (int i = 0; i < 4; ++i) {
      int chunk = i * 256 + tid;
      int row = chunk >> 3, f4 = chunk & 7;
      floatx4 wv = *(const floatx4*)(W + (size_t)(n0 + row) * ldw + k0 + f4 * 4);
      short4v wb;
#pragma unroll
      for (int j = 0; j < 4; ++j) wb[j] = f2bf(wv[j]);
      int soff = row * 32 + (((f4 >> 1) ^ ((row >> 1) & 3)) << 3) + (f4 & 1) * 4;
      *(short4v*)(Bs + soff) = wb;
    }
    __syncthreads();

    short8 af[4], bfr[4];
#pragma unroll
    for (int mi = 0; mi < 4; ++mi) {
      int row = wr * 64 + mi * 16 + lrow;
      af[mi] = *(const short8*)(As + row * 32 + ((lgrp ^ ((lrow >> 1) & 3)) << 3));
    }
#pragma unroll
    for (int ni = 0; ni < 4; ++ni) {
      int row = wc * 64 + ni * 16 + lrow;
      bfr[ni] = *(const short8*)(Bs + row * 32 + ((lgrp ^ ((lrow >> 1) & 3)) << 3));
    }
#pragma unroll
    for (int mi = 0; mi < 4; ++mi)
#pragma unroll
      for (int ni = 0; ni < 4; ++ni)
        acc[mi][ni] = __builtin_amdgcn_mfma_f32_16x16x32_bf16(
            af[mi], bfr[ni], acc[mi][ni], 0, 0, 0);
    __syncthreads();
  }

  // epilogue: C/D layout col=lane&15, row=(lane>>4)*4+reg
#pragma unroll
  for (int mi = 0; mi < 4; ++mi) {
#pragma unroll
    for (int ni = 0; ni < 4; ++ni) {
      int row = m0 + wr * 64 + mi * 16 + lgrp * 4;
      int col = n0 + wc * 64 + ni * 16 + lrow;
      if (EPI == 0) {
#pragma unroll
        for (int r = 0; r < 4; ++r)
          ((short*)Yv)[(size_t)(row + r) * ldy + col] = f2bf(acc[mi][ni][r]);
      } else if (EPI == 1) {
#pragma unroll
        for (int r = 0; r < 4; ++r)
          ((float*)Yv)[(size_t)(row + r) * ldy + col] = acc[mi][ni][r];
      } else {
        short4v p;
#pragma unroll
        for (int r = 0; r < 4; ++r) p[r] = f2bf(acc[mi][ni][r]);
        *(short4v*)((short*)Yv + (size_t)col * ldy + row) = p;
      }
    }
  }
}

// ---------------- fused QKV projection ----------------
// grid (24, 32): nt 0..15 -> q (row-major), 16..19 -> k (row-major),
// 20..23 -> v (TRANSPOSED: vt[col][token], ldy=4096)
__global__ __launch_bounds__(256) void qkv_kernel(
    const float* __restrict__ x, const float* __restrict__ wq,
    const float* __restrict__ wk, const float* __restrict__ wv,
    short* __restrict__ q, short* __restrict__ k, short* __restrict__ vt)
{
  __shared__ __align__(16) short As[128 * 32];
  __shared__ __align__(16) short Bs[128 * 32];
  int nt = blockIdx.x, mt = blockIdx.y;
  if (nt < 16) {
    gemm_core_128<false, 0>(x, wq, q, mt * 128, nt * 128, 2048, 2048, 2048, 2048, As, Bs);
  } else if (nt < 20) {
    gemm_core_128<false, 0>(x, wk, k, mt * 128, (nt - 16) * 128, 2048, 2048, 2048, 512, As, Bs);
  } else {
    gemm_core_128<false, 2>(x, wv, vt, mt * 128, (nt - 20) * 128, 2048, 2048, 2048, 4096, As, Bs);
  }
}

// ---------------- output projection (A = bf16 attn-out, Y = fp32) -------------
__global__ __launch_bounds__(256) void oproj_kernel(
    const short* __restrict__ a, const float* __restrict__ wo, float* __restrict__ y)
{
  __shared__ __align__(16) short As[128 * 32];
  __shared__ __align__(16) short Bs[128 * 32];
  gemm_core_128<true, 1>(a, wo, y, blockIdx.y * 128, blockIdx.x * 128,
                         2048, 2048, 2048, 2048, As, Bs);
}

// ---------------- RoPE (in-place on q and k; fp32 cos/sin tables) -------------
__global__ void rope_kernel(short* __restrict__ q, short* __restrict__ k,
                            const float* __restrict__ ct, const float* __restrict__ st)
{
  const int NQ = 4096 * 1024;
  const int NK = 4096 * 256;
  int idx = blockIdx.x * blockDim.x + threadIdx.x;
  int total = NQ + NK;
  for (int p = idx; p < total; p += gridDim.x * blockDim.x) {
    short* base; int tok, i, off;
    if (p < NQ) {
      tok = p >> 10; int rem = p & 1023;
      i = rem & 31;
      base = q; off = tok * 2048 + rem * 2;
    } else {
      int pp = p - NQ;
      tok = pp >> 8; int rem = pp & 255;
      i = rem & 31;
      base = k; off = tok * 512 + rem * 2;
    }
    int s = tok & 2047;
    float c  = ct[s * 32 + i];
    float sn = st[s * 32 + i];
    unsigned int u = *(unsigned int*)(base + off);
    float xr = bf2f((short)(u & 0xffff));
    float xi = bf2f((short)(u >> 16));
    float orr = xr * c - xi * sn;
    float oi  = xr * sn + xi * c;
    unsigned int o = ((unsigned int)(unsigned short)f2bf(orr)) |
                     (((unsigned int)(unsigned short)f2bf(oi)) << 16);
    *(unsigned int*)(base + off) = o;
  }
}

// ---------------- flash attention (causal, GQA 4:1, paired q-tiles) -----------
// grid (16, 32, 2) = (q-tile pair, hq, b). Block handles q-tiles qp and 31-qp,
// sharing one kv sweep (tiles 0..31-qp; low tile active while t <= qp).
// K and V^T tiles staged via GLDS16 with XOR-swizzle (c16 ^= row&7) applied by
// pre-swizzling the per-lane GLOBAL source; LDS stays linear; reads swizzled.
__global__ __launch_bounds__(256) void attn_kernel(
    const short* qws, const short* __restrict__ kws,
    const short* __restrict__ vt, short* ows)
{
  int qp = blockIdx.x;
  int hq = blockIdx.y;
  int b  = blockIdx.z;
  int h  = hq >> 2;
  int tid = threadIdx.x;
  int w = tid >> 6, l = tid & 63;
  int lrow = l & 15, lgrp = l >> 4;

  __shared__ __align__(16) short Ks[64 * 64];
  __shared__ __align__(16) short Vs[64 * 64];      // V^T tile: [d][j]
  __shared__ __align__(16) short Ps[4 * 16 * 72];
  short* myPs = Ps + w * 16 * 72;

  int rowA0 = qp * 64 + w * 16;
  int rowB0 = (31 - qp) * 64 + w * 16;

  short8 qfA[2], qfB[2];
  {
    const short* p = qws + ((size_t)(b * 2048 + rowA0 + lrow) * 32 + hq) * 64 + lgrp * 8;
    qfA[0] = *(const short8*)p; qfA[1] = *(const short8*)(p + 32);
    p = qws + ((size_t)(b * 2048 + rowB0 + lrow) * 32 + hq) * 64 + lgrp * 8;
    qfB[0] = *(const short8*)p; qfB[1] = *(const short8*)(p + 32);
  }

  floatx4 oA[4], oB[4];
  float mA[4], lA[4], mB[4], lB[4];
#pragma unroll
  for (int i = 0; i < 4; ++i) {
    oA[i] = (floatx4){0.f, 0.f, 0.f, 0.f};
    oB[i] = (floatx4){0.f, 0.f, 0.f, 0.f};
    mA[i] = -1e30f; lA[i] = 0.f; mB[i] = -1e30f; lB[i] = 0.f;
  }

  int ntiles = 32 - qp;
  for (int t = 0; t < ntiles; ++t) {
    int kv0 = t * 64;
    // stage K tile [64 j][64 d] and V^T tile [64 d][64 j], swizzled source
#pragma unroll
    for (int i = 0; i < 2; ++i) {
      int cc = i * 256 + w * 64 + l;         // [0,512)
      int row = cc >> 3;
      int c16 = (cc & 7) ^ (row & 7);        // inverse swizzle on source
      GLDS16(kws + (size_t)(b * 2048 + kv0 + row) * 512 + h * 64 + c16 * 8,
             (char*)Ks + (i * 256 + w * 64) * 16);
      GLDS16(vt + (size_t)(h * 64 + row) * 4096 + b * 2048 + kv0 + c16 * 8,
             (char*)Vs + (i * 256 + w * 64) * 16);
    }
    __syncthreads();

    auto process = [&](const short8* qf, int qrow0, floatx4* oacc,
                       float* m_run, float* l_run) {
      floatx4 sf[4];
#pragma unroll
      for (int nj = 0; nj < 4; ++nj) {
        floatx4 sa = (floatx4){0.f, 0.f, 0.f, 0.f};
#pragma unroll
        for (int kk = 0; kk < 2; ++kk) {
          int row = nj * 16 + lrow;
          short8 kf = *(const short8*)(
              Ks + row * 64 + ((((kk << 2) | lgrp) ^ (lrow & 7)) << 3));
          sa = __builtin_amdgcn_mfma_f32_16x16x32_bf16(qf[kk], kf, sa, 0, 0, 0);
        }
        sf[nj] = sa;
      }
      int qi0 = qrow0 + lgrp * 4;
#pragma unroll
      for (int nj = 0; nj < 4; ++nj) {
        int kj = kv0 + nj * 16 + lrow;
#pragma unroll
        for (int r = 0; r < 4; ++r) {
          float sv = sf[nj][r] * 0.125f;
          sf[nj][r] = (kj <= qi0 + r) ? sv : -1e30f;
        }
      }
      float tmax[4];
#pragma unroll
      for (int r = 0; r < 4; ++r)
        tmax[r] = fmaxf(fmaxf(sf[0][r], sf[1][r]), fmaxf(sf[2][r], sf[3][r]));
#pragma unroll
      for (int msk = 1; msk <= 8; msk <<= 1)
#pragma unroll
        for (int r = 0; r < 4; ++r)
          tmax[r] = fmaxf(tmax[r], __shfl_xor(tmax[r], msk, 64));
      float corr[4];
#pragma unroll
      for (int r = 0; r < 4; ++r) {
        float mnew = fmaxf(m_run[r], tmax[r]);
        corr[r] = __expf(m_run[r] - mnew);
        m_run[r] = mnew;
      }
      float rsum[4] = {0.f, 0.f, 0.f, 0.f};
#pragma unroll
      for (int nj = 0; nj < 4; ++nj)
#pragma unroll
        for (int r = 0; r < 4; ++r) {
          float pv = __expf(sf[nj][r] - m_run[r]);
          sf[nj][r] = pv;
          rsum[r] += pv;
        }
#pragma unroll
      for (int msk = 1; msk <= 8; msk <<= 1)
#pragma unroll
        for (int r = 0; r < 4; ++r)
          rsum[r] += __shfl_xor(rsum[r], msk, 64);
#pragma unroll
      for (int r = 0; r < 4; ++r) l_run[r] = l_run[r] * corr[r] + rsum[r];
#pragma unroll
      for (int d0 = 0; d0 < 4; ++d0)
#pragma unroll
        for (int r = 0; r < 4; ++r) oacc[d0][r] *= corr[r];

      // P (C-layout) -> per-wave LDS region (in-order DS pipe within wave;
      // sched_barrier pins compiler ordering)
#pragma unroll
      for (int nj = 0; nj < 4; ++nj)
#pragma unroll
        for (int r = 0; r < 4; ++r)
          myPs[(lgrp * 4 + r) * 72 + nj * 16 + lrow] = f2bf(sf[nj][r]);
      __builtin_amdgcn_sched_barrier(0);

#pragma unroll
      for (int kk2 = 0; kk2 < 2; ++kk2) {
        short8 pa = *(const short8*)(myPs + lrow * 72 + kk2 * 32 + lgrp * 8);
#pragma unroll
        for (int d0 = 0; d0 < 4; ++d0) {
          int row = d0 * 16 + lrow;
          short8 vf = *(const short8*)(
              Vs + row * 64 + ((((kk2 << 2) | lgrp) ^ (lrow & 7)) << 3));
          oacc[d0] = __builtin_amdgcn_mfma_f32_16x16x32_bf16(pa, vf, oacc[d0], 0, 0, 0);
        }
      }
      __builtin_amdgcn_sched_barrier(0);
    };

    process(qfB, rowB0, oB, mB, lB);
    if (t <= qp) process(qfA, rowA0, oA, mA, lA);
    __syncthreads();
  }

  // epilogue (attn-out written in-place over q buffer; own rows only)
#pragma unroll
  for (int d0 = 0; d0 < 4; ++d0)
#pragma unroll
    for (int r = 0; r < 4; ++r) {
      size_t tB = (size_t)(b * 2048 + rowB0 + lgrp * 4 + r);
      ows[(tB * 32 + hq) * 64 + d0 * 16 + lrow] = f2bf(oB[d0][r] / lB[r]);
      size_t tA = (size_t)(b * 2048 + rowA0 + lgrp * 4 + r);
      ows[(tA * 32 + hq) * 64 + d0 * 16 + lrow] = f2bf(oA[d0][r] / lA[r]);
    }
}

extern "C" void kernel_launch(void* const* d_in, const int* in_sizes, int n_in,
                              void* d_out, int out_size, void* d_ws, size_t ws_size,
                              hipStream_t stream) {
  (void)in_sizes; (void)n_in; (void)out_size; (void)ws_size;
  const float* x  = (const float*)d_in[0];
  const float* wq = (const float*)d_in[1];
  const float* wk = (const float*)d_in[2];
  const float* wv = (const float*)d_in[3];
  const float* wo = (const float*)d_in[4];
  const float* ct = (const float*)d_in[5];
  const float* st = (const float*)d_in[6];
  float* out = (float*)d_out;

  // workspace (bf16): q 16MB (attn-out in-place) + k 4MB + v^T 4MB = 24MB
  short* q_ws  = (short*)d_ws;                     // [4096][2048]
  short* k_ws  = q_ws + (size_t)4096 * 2048;       // [4096][512]
  short* vt_ws = k_ws + (size_t)4096 * 512;        // [512][4096] (transposed)

  qkv_kernel<<<dim3(24, 32), 256, 0, stream>>>(x, wq, wk, wv, q_ws, k_ws, vt_ws);
  rope_kernel<<<dim3(2048), 256, 0, stream>>>(q_ws, k_ws, ct, st);
  attn_kernel<<<dim3(16, 32, 2), 256, 0, stream>>>(q_ws, k_ws, vt_ws, q_ws);
  oproj_kernel<<<dim3(16, 32), 256, 0, stream>>>(q_ws, wo, out);
}